// Round 3
// baseline (476.249 us; speedup 1.0000x reference)
//
#include <hip/hip_runtime.h>

// Problem geometry (fixed by the reference).
#define NFRAMES 64
#define HH 1024
#define WW 1024
// quads per frame = H * (W/4) = 1024 * 256 = 2^18
#define QPF_SHIFT 18
#define QPF_MASK  ((1 << QPF_SHIFT) - 1)
#define W4_SHIFT  8   // W/4 = 256
#define W4_MASK   255

// JAX map_coordinates mode='mirror' index fixer: |((idx + s) mod 2s) - s|,
// s = size-1, applied to the INTEGER corner indices (floor(c) and floor(c)+1).
__device__ __forceinline__ int mirror_fix(int idx, int s, int m) {
    int t = (idx + s) % m;
    if (t < 0) t += m;
    t -= s;
    return t < 0 ? -t : t;
}

__global__ __launch_bounds__(256) void
flux_shift_kernel(const float* __restrict__ in,    // [N, H, W]
                  const float* __restrict__ flux,  // [N]
                  const float* __restrict__ noise, // [N]
                  const float* __restrict__ dydx,  // [N, 2]
                  float* __restrict__ out,         // [N, H, W]
                  int total_quads) {
    const int stride = gridDim.x * blockDim.x;
    for (int q = blockIdx.x * blockDim.x + threadIdx.x; q < total_quads; q += stride) {
        // n is wave-uniform: waves are 64-aligned in quad space, 64 | 2^18.
        const int n   = __builtin_amdgcn_readfirstlane(q >> QPF_SHIFT);
        const int rem = q & QPF_MASK;
        const int y   = rem >> W4_SHIFT;
        const int x   = (rem & W4_MASK) << 2;

        // Frame params via scalar loads (uniform n -> s_load).
        const float dy = dydx[2 * n];
        const float dx = dydx[2 * n + 1];
        const float fl = flux[n];
        const float bi = noise[n];

        // coordinate = y - dy; floor = y + floor(-dy); frac = frame-constant.
        const float nky = floorf(-dy);
        const float nkx = floorf(-dx);
        const float fy = -dy - nky;          // in [0,1)
        const float fx = -dx - nkx;
        const int ky = __builtin_amdgcn_readfirstlane((int)nky);
        const int kx = __builtin_amdgcn_readfirstlane((int)nkx);

        const int ry0 = y + ky;              // lower row index (unfixed)
        const int cx0 = x + kx;              // lower col index of pixel 0 (unfixed)
        // x % 4 == 0 so (cx0 & 3) == (kx & 3): wave-uniform select offset.
        const int o = kx & 3;
        const int A = cx0 - o;               // 16B-aligned window start; cols A..A+7

        const float* __restrict__ base = in + (size_t)n * (HH * WW);
        const float gy = 1.0f - fy;
        const float gx = 1.0f - fx;

        float4 ovec;
        if (ry0 >= 0 && ry0 <= HH - 2 && A >= 0 && A <= WW - 8) {
            // Interior fast path: 4 aligned float4 loads cover both rows.
            const float* __restrict__ r0 = base + (size_t)ry0 * WW + A;
            const float4 p0 = *reinterpret_cast<const float4*>(r0);
            const float4 p1 = *reinterpret_cast<const float4*>(r0 + 4);
            const float4 q0 = *reinterpret_cast<const float4*>(r0 + WW);
            const float4 q1 = *reinterpret_cast<const float4*>(r0 + WW + 4);

            // Uniform switch = pure register renaming (no VALU, s_cbranch).
            float a0, a1, a2, a3, a4, b0, b1, b2, b3, b4;
            switch (o) {
                case 0:  a0=p0.x; a1=p0.y; a2=p0.z; a3=p0.w; a4=p1.x;
                         b0=q0.x; b1=q0.y; b2=q0.z; b3=q0.w; b4=q1.x; break;
                case 1:  a0=p0.y; a1=p0.z; a2=p0.w; a3=p1.x; a4=p1.y;
                         b0=q0.y; b1=q0.z; b2=q0.w; b3=q1.x; b4=q1.y; break;
                case 2:  a0=p0.z; a1=p0.w; a2=p1.x; a3=p1.y; a4=p1.z;
                         b0=q0.z; b1=q0.w; b2=q1.x; b3=q1.y; b4=q1.z; break;
                default: a0=p0.w; a1=p1.x; a2=p1.y; a3=p1.z; a4=p1.w;
                         b0=q0.w; b1=q1.x; b2=q1.y; b3=q1.z; b4=q1.w; break;
            }
            // Vertical lerp (frame-constant fy), then horizontal lerp (fx).
            const float t0 = gy * a0 + fy * b0;
            const float t1 = gy * a1 + fy * b1;
            const float t2 = gy * a2 + fy * b2;
            const float t3 = gy * a3 + fy * b3;
            const float t4 = gy * a4 + fy * b4;
            ovec.x = (gx * t0 + fx * t1) * fl + bi;
            ovec.y = (gx * t1 + fx * t2) * fl + bi;
            ovec.z = (gx * t2 + fx * t3) * fl + bi;
            ovec.w = (gx * t3 + fx * t4) * fl + bi;
        } else {
            // Border path: full mirror fixing per corner index.
            const int sh = HH - 1, mh = 2 * sh;
            const int sw = WW - 1, mw = 2 * sw;
            const int iy0 = mirror_fix(ry0,     sh, mh);
            const int iy1 = mirror_fix(ry0 + 1, sh, mh);
            const float* __restrict__ r0 = base + (size_t)iy0 * WW;
            const float* __restrict__ r1 = base + (size_t)iy1 * WW;
            float res[4];
            #pragma unroll
            for (int j = 0; j < 4; ++j) {
                const int c0 = mirror_fix(cx0 + j,     sw, mw);
                const int c1 = mirror_fix(cx0 + j + 1, sw, mw);
                const float t0 = gy * r0[c0] + fy * r1[c0];
                const float t1 = gy * r0[c1] + fy * r1[c1];
                res[j] = (gx * t0 + fx * t1) * fl + bi;
            }
            ovec = make_float4(res[0], res[1], res[2], res[3]);
        }
        *reinterpret_cast<float4*>(out + (size_t)q * 4) = ovec;
    }
}

extern "C" void kernel_launch(void* const* d_in, const int* in_sizes, int n_in,
                              void* d_out, int out_size, void* d_ws, size_t ws_size,
                              hipStream_t stream) {
    const float* in    = (const float*)d_in[0]; // [1, N, H, W, 1]
    const float* flux  = (const float*)d_in[1]; // [N,1,1,1]
    const float* noise = (const float*)d_in[2]; // [N,1,1,1]
    const float* dydx  = (const float*)d_in[3]; // [N,2]
    float* out = (float*)d_out;

    const int total_quads = NFRAMES * HH * (WW / 4); // 16,777,216
    const int block = 256;
    const int grid  = 2048; // 8 blocks/CU on 256 CUs; grid-stride covers the rest

    flux_shift_kernel<<<grid, block, 0, stream>>>(in, flux, noise, dydx, out, total_quads);
}

// Round 6
// 440.962 us; speedup vs baseline: 1.0800x; 1.0800x over previous
//
#include <hip/hip_runtime.h>

// Problem geometry (fixed by the reference).
#define NFRAMES 64
#define HH 1024
#define WW 1024

// JAX map_coordinates mode='mirror' index fixer: |((idx + s) mod 2s) - s|,
// s = size-1, applied to the INTEGER corner indices (floor(c) and floor(c)+1).
__device__ __forceinline__ int mirror_fix(int idx, int s, int m) {
    int t = (idx + s) % m;
    if (t < 0) t += m;
    t -= s;
    return t < 0 ? -t : t;
}

// Fully-static interior patch compute: 5x2 float4 window -> 4x4 outputs.
// O = frame-uniform sub-quad offset (kx & 3). All register indices static.
template<int O>
__device__ __forceinline__ void compute_patch(const float4 (&L)[5][2],
                                              float fy, float gy,
                                              float fx, float gx,
                                              float fl, float bi,
                                              float4 (&res)[4]) {
    float w[5][5];
    #pragma unroll
    for (int r = 0; r < 5; ++r) {
        const float* f = reinterpret_cast<const float*>(&L[r][0]); // 8 floats
        #pragma unroll
        for (int c = 0; c < 5; ++c) w[r][c] = f[O + c];            // static idx
    }
    #pragma unroll
    for (int r = 0; r < 4; ++r) {
        float t[5];
        #pragma unroll
        for (int c = 0; c < 5; ++c) t[c] = gy * w[r][c] + fy * w[r + 1][c];
        res[r].x = (gx * t[0] + fx * t[1]) * fl + bi;
        res[r].y = (gx * t[1] + fx * t[2]) * fl + bi;
        res[r].z = (gx * t[2] + fx * t[3]) * fl + bi;
        res[r].w = (gx * t[3] + fx * t[4]) * fl + bi;
    }
}

__global__ __launch_bounds__(256) void
flux_shift_kernel(const float* __restrict__ in,    // [N, H, W]
                  const float* __restrict__ flux,  // [N]
                  const float* __restrict__ noise, // [N]
                  const float* __restrict__ dydx,  // [N, 2]
                  float* __restrict__ out) {       // [N, H, W]
    // One block = one 4-row x 1024-col band. 256 bands/frame, 64 frames.
    const int band = blockIdx.x & 255;
    const int n    = blockIdx.x >> 8;        // block-uniform -> scalar
    const int y0   = band << 2;
    const int x    = threadIdx.x << 2;       // first output col of this thread

    // Frame params (uniform n -> s_load).
    const float dy = dydx[2 * n];
    const float dx = dydx[2 * n + 1];
    const float fl = flux[n];
    const float bi = noise[n];

    const float nky = floorf(-dy);
    const float nkx = floorf(-dx);
    const float fy = -dy - nky;              // frame-constant fractions
    const float fx = -dx - nkx;
    const int ky = (int)nky;
    const int kx = (int)nkx;
    const float gy = 1.0f - fy;
    const float gx = 1.0f - fx;

    const int ry = y0 + ky;                  // need input rows ry..ry+4
    const int o  = kx & 3;                   // frame-uniform select offset
    const int A  = x + kx - o;               // 16B-aligned window, cols A..A+7

    const float* __restrict__ base = in + (size_t)n * (HH * WW);
    float* __restrict__ ob = out + (size_t)n * (HH * WW) + (size_t)y0 * WW + x;

    if (ry >= 0 && ry + 4 <= HH - 1 && A >= 0 && A <= WW - 8) {
        // Interior fast path: 10 independent aligned float4 loads (deep MLP).
        const float* __restrict__ p = base + (size_t)ry * WW + A;
        float4 L[5][2];
        #pragma unroll
        for (int r = 0; r < 5; ++r) {
            L[r][0] = *reinterpret_cast<const float4*>(p + (size_t)r * WW);
            L[r][1] = *reinterpret_cast<const float4*>(p + (size_t)r * WW + 4);
        }
        float4 res[4];
        switch (o) {  // block-uniform: one scalar branch, all-static bodies
            case 0:  compute_patch<0>(L, fy, gy, fx, gx, fl, bi, res); break;
            case 1:  compute_patch<1>(L, fy, gy, fx, gx, fl, bi, res); break;
            case 2:  compute_patch<2>(L, fy, gy, fx, gx, fl, bi, res); break;
            default: compute_patch<3>(L, fy, gy, fx, gx, fl, bi, res); break;
        }
        #pragma unroll
        for (int r = 0; r < 4; ++r)
            *reinterpret_cast<float4*>(ob + (size_t)r * WW) = res[r];
    } else {
        // Border path: full mirror fixing per corner index, per output row.
        const int sh = HH - 1, mh = 2 * sh;
        const int sw = WW - 1, mw = 2 * sw;
        const int cx0 = x + kx;
        #pragma unroll
        for (int r = 0; r < 4; ++r) {
            const int iy0 = mirror_fix(y0 + r + ky,     sh, mh);
            const int iy1 = mirror_fix(y0 + r + ky + 1, sh, mh);
            const float* __restrict__ r0 = base + (size_t)iy0 * WW;
            const float* __restrict__ r1 = base + (size_t)iy1 * WW;
            float res[4];
            #pragma unroll
            for (int j = 0; j < 4; ++j) {
                const int c0 = mirror_fix(cx0 + j,     sw, mw);
                const int c1 = mirror_fix(cx0 + j + 1, sw, mw);
                const float t0 = gy * r0[c0] + fy * r1[c0];
                const float t1 = gy * r0[c1] + fy * r1[c1];
                res[j] = (gx * t0 + fx * t1) * fl + bi;
            }
            *reinterpret_cast<float4*>(ob + (size_t)r * WW) =
                make_float4(res[0], res[1], res[2], res[3]);
        }
    }
}

extern "C" void kernel_launch(void* const* d_in, const int* in_sizes, int n_in,
                              void* d_out, int out_size, void* d_ws, size_t ws_size,
                              hipStream_t stream) {
    const float* in    = (const float*)d_in[0]; // [1, N, H, W, 1]
    const float* flux  = (const float*)d_in[1]; // [N,1,1,1]
    const float* noise = (const float*)d_in[2]; // [N,1,1,1]
    const float* dydx  = (const float*)d_in[3]; // [N,2]
    float* out = (float*)d_out;

    // 64 frames x 256 bands (4 rows each) = 16384 blocks, single-shot.
    const int grid  = NFRAMES * (HH / 4);
    const int block = 256;

    flux_shift_kernel<<<grid, block, 0, stream>>>(in, flux, noise, dydx, out);
}